// Round 2
// baseline (109.546 us; speedup 1.0000x reference)
//
#include <hip/hip_runtime.h>

// DecoderLayer: out[k,n,m] = tanh(sum_p w[k,p]*prev[idx[k,p],n,m] + b[k]),
// gated by (#active parents >= 12).  M=2048, K=4096, N=64 (NN=4096), P=16.

#define M_ROWS   2048
#define K_NODES  4096
#define NN       4096      // 64*64 flattened positions
#define P_PAR    16
#define POS_TILE 8
#define ROW_STRIDE 12      // floats per staged row (8 used + 4 pad) -> conflict-spread, 16B aligned
#define LDS_BYTES (M_ROWS * ROW_STRIDE * 4)   // 98304 B = 96 KiB
#define OUT_ELEMS (K_NODES * NN)
#define ACTIVE_THRESHOLD 12

typedef float f32x4 __attribute__((ext_vector_type(4)));   // native vector type
                                                           // (nontemporal builtin needs this)

__device__ __forceinline__ float fast_tanh(float x) {
  float ax = __builtin_fabsf(x);
  float e  = __expf(-2.0f * ax);                       // v_exp_f32 path
  float r  = (1.0f - e) * __builtin_amdgcn_rcpf(1.0f + e);
  return __builtin_copysignf(r, x);
}

// Computes the activity gate per node and writes out_active (as 0.0/1.0 float).
// Runtime-detects whether prev_is_active arrived as int32 words or packed bytes:
// scanning the first 2048 BYTES reinterpreted as 512 words, any word > 1 implies
// byte packing (0x01010101 etc.); a true int32 bool array only has words 0/1.
__global__ __launch_bounds__(256) void act_kernel(
    const int* __restrict__ pidx, const unsigned int* __restrict__ isact,
    float* __restrict__ outact) {
  __shared__ int mode_sh;
  if (threadIdx.x == 0) mode_sh = 0;
  __syncthreads();
  int bad = 0;
  for (int i = threadIdx.x; i < 512; i += 256) {   // first 2048 bytes only (safe in both modes)
    if (isact[i] > 1u) bad = 1;
  }
  if (bad) atomicOr(&mode_sh, 1);
  __syncthreads();
  const int bytemode = mode_sh;

  int k = blockIdx.x * 256 + threadIdx.x;
  const int4* ip = (const int4*)(pidx + k * P_PAR);
  int4 ia = ip[0], ib = ip[1], ic = ip[2], id4 = ip[3];
  int ids[16] = {ia.x, ia.y, ia.z, ia.w, ib.x, ib.y, ib.z, ib.w,
                 ic.x, ic.y, ic.z, ic.w, id4.x, id4.y, id4.z, id4.w};
  int n = 0;
  #pragma unroll
  for (int p = 0; p < 16; ++p) {
    int id = ids[p];
    unsigned a = bytemode ? (unsigned)((const unsigned char*)isact)[id]
                          : isact[id];
    n += (a != 0u);
  }
  outact[k] = (n >= ACTIVE_THRESHOLD) ? 1.0f : 0.0f;
}

__global__ __launch_bounds__(256) void decoder_kernel(
    const float* __restrict__ prev, const int* __restrict__ pidx,
    const float* __restrict__ w, const float* __restrict__ b,
    const float* __restrict__ actf, float* __restrict__ out) {
  extern __shared__ float xs[];   // [M_ROWS][ROW_STRIDE]

  // XCD-chunked swizzle: adjacent pos-tiles (which share 64B output/input lines)
  // land on the same XCD so L2 merges half-line writes before HBM.
  int bid  = blockIdx.x;                       // 0..511
  int tile = (bid & 7) * (NN / POS_TILE / 8) + (bid >> 3);
  int pos0 = tile * POS_TILE;

  // ---- stage x[row][0..7] = prev[row, pos0..pos0+7] into LDS ----
  #pragma unroll
  for (int it = 0; it < (M_ROWS * 2) / 256; ++it) {     // 16 iters
    int linear = (it << 8) + threadIdx.x;               // 0..4095
    int row  = linear >> 1;
    int half = linear & 1;
    float4 v = *(const float4*)(prev + row * NN + pos0 + (half << 2));
    *(float4*)(&xs[row * ROW_STRIDE + (half << 2)]) = v;
  }
  __syncthreads();

  // ---- each thread owns one node k per iteration, all 8 positions ----
  for (int kk = 0; kk < K_NODES / 256; ++kk) {          // 16 iters
    int k = (kk << 8) + threadIdx.x;
    const int4*   ip  = (const int4*)(pidx + (k << 4));
    const float4* wp4 = (const float4*)(w + (k << 4));
    int4   ia = ip[0],  ib = ip[1],  ic = ip[2],  id4 = ip[3];
    float4 wa = wp4[0], wb = wp4[1], wc = wp4[2], wd = wp4[3];
    int ids[16] = {ia.x, ia.y, ia.z, ia.w, ib.x, ib.y, ib.z, ib.w,
                   ic.x, ic.y, ic.z, ic.w, id4.x, id4.y, id4.z, id4.w};
    float ws[16] = {wa.x, wa.y, wa.z, wa.w, wb.x, wb.y, wb.z, wb.w,
                    wc.x, wc.y, wc.z, wc.w, wd.x, wd.y, wd.z, wd.w};
    float bk = b[k];
    float acc[8];
    #pragma unroll
    for (int j = 0; j < 8; ++j) acc[j] = bk;

    #pragma unroll
    for (int p = 0; p < 16; ++p) {
      const float* rp = &xs[ids[p] * ROW_STRIDE];
      float4 lo = *(const float4*)rp;          // ds_read_b128
      float4 hi = *(const float4*)(rp + 4);    // ds_read_b128
      float wpv = ws[p];
      acc[0] += wpv * lo.x; acc[1] += wpv * lo.y;
      acc[2] += wpv * lo.z; acc[3] += wpv * lo.w;
      acc[4] += wpv * hi.x; acc[5] += wpv * hi.y;
      acc[6] += wpv * hi.z; acc[7] += wpv * hi.w;
    }

    float g = actf[k];   // 0.0 or 1.0
    f32x4 o0, o1;
    o0.x = fast_tanh(acc[0]) * g; o0.y = fast_tanh(acc[1]) * g;
    o0.z = fast_tanh(acc[2]) * g; o0.w = fast_tanh(acc[3]) * g;
    o1.x = fast_tanh(acc[4]) * g; o1.y = fast_tanh(acc[5]) * g;
    o1.z = fast_tanh(acc[6]) * g; o1.w = fast_tanh(acc[7]) * g;

    float* op = out + (size_t)k * NN + pos0;
    __builtin_nontemporal_store(o0, (f32x4*)op);
    __builtin_nontemporal_store(o1, (f32x4*)(op + 4));
  }
}

extern "C" void kernel_launch(void* const* d_in, const int* in_sizes, int n_in,
                              void* d_out, int out_size, void* d_ws, size_t ws_size,
                              hipStream_t stream) {
  const float* prev  = (const float*)d_in[0];
  const void*  isact = d_in[1];
  const int*   pidx  = (const int*)d_in[2];
  const float* w     = (const float*)d_in[3];
  const float* b     = (const float*)d_in[4];
  float* out    = (float*)d_out;
  float* outact = out + OUT_ELEMS;

  (void)hipFuncSetAttribute((const void*)decoder_kernel,
                            hipFuncAttributeMaxDynamicSharedMemorySize, LDS_BYTES);

  act_kernel<<<K_NODES / 256, 256, 0, stream>>>(
      pidx, (const unsigned int*)isact, outact);
  decoder_kernel<<<NN / POS_TILE, 256, LDS_BYTES, stream>>>(
      prev, pidx, w, b, outact, out);
}